// Round 3
// baseline (344.752 us; speedup 1.0000x reference)
//
#include <hip/hip_runtime.h>

namespace {

typedef __attribute__((ext_vector_type(8)))  short          short8;
typedef __attribute__((ext_vector_type(8)))  unsigned short u16x8;
typedef __attribute__((ext_vector_type(4)))  unsigned short u16x4;
typedef __attribute__((ext_vector_type(4)))  float          f32x4;

constexpr int V  = 200;
constexpr int F  = 64;
constexpr int NT = 512;   // N*T

// ---- ws layout (bytes) ----
constexpr size_t WS_XT  = 0;            // ushort [512][64][224] = 14,680,064  (x^T bf16, zero-padded u>=200)
constexpr size_t WS_THT = 14680064;     // ushort [3][64][64]    =     24,576

__device__ __forceinline__ unsigned short f2bf(float x) {
    union { float f; unsigned u; } c; c.f = x;
    unsigned r = c.u + 0x7FFF + ((c.u >> 16) & 1);
    return (unsigned short)(r >> 16);
}

// ============ P: xT[b][f][u] = bf16(x[b][u][f]) (513th block: ThT) ============
__global__ __launch_bounds__(256)
void prep_misc(const float* __restrict__ x,
               const float* __restrict__ Theta,
               unsigned short* __restrict__ xT,
               unsigned short* __restrict__ thT)
{
    __shared__ __align__(16) char smem[30464];
    const int bb = blockIdx.x, tid = threadIdx.x;
    if (bb < NT) {
        unsigned short* xs = (unsigned short*)smem;    // [224][68] bf16
        const float* __restrict__ xp = x + (size_t)bb * (V * F);
        for (int idx = tid; idx < 224 * 16; idx += 256) {
            const int u = idx >> 4, fg = idx & 15;
            u16x4 w; w[0] = 0; w[1] = 0; w[2] = 0; w[3] = 0;
            if (u < V) {
                const float4 v4 = *(const float4*)&xp[u * F + 4 * fg];
                w[0] = f2bf(v4.x); w[1] = f2bf(v4.y); w[2] = f2bf(v4.z); w[3] = f2bf(v4.w);
            }
            *(u16x4*)&xs[u * 68 + 4 * fg] = w;
        }
        __syncthreads();
        unsigned short* xo = xT + (size_t)bb * (64 * 224);
        for (int it = 0; it < 8; ++it) {
            const int wid = tid + 256 * it;            // 0..2047
            const int f = wid >> 5, sl = wid & 31;     // 64 f-rows x 32 slots (28 valid)
            if (sl < 28) {
                u16x8 w;
                #pragma unroll
                for (int j = 0; j < 8; ++j) w[j] = xs[(8 * sl + j) * 68 + f];
                *(u16x8*)&xo[f * 224 + 8 * sl] = w;    // 448B contiguous per f-row
            }
        }
    } else {
        float* T = (float*)smem;                       // [64][65] f32
        for (int k = 0; k < 3; ++k) {
            __syncthreads();
            for (int idx = tid; idx < 4096; idx += 256)
                T[(idx >> 6) * 65 + (idx & 63)] = Theta[k * 4096 + idx];
            __syncthreads();
            for (int idx = tid; idx < 4096; idx += 256) {
                const int fo = idx >> 6, f = idx & 63;
                thT[k * 4096 + fo * 64 + f] = f2bf(T[f * 65 + fo]);
            }
        }
    }
}

// ============ G: fully fused kernel ============
// grid (1024) = (b, v-half). Per block: 112 (h=0) or 96 (h=1) v-rows.
// Per kt (32 u's): stage S^T slab (reg-prefetched) -> build A1/A2 bf16 in LDS
// (A1=-m*Att[u][v], A2=2m^2*Att[u][v], m=min(S[v][u],S[u][v])) + accumulate
// d[v] -> MFMA. Epilogue: Chebyshev diag terms + Theta contraction + relu.
__global__ __launch_bounds__(256, 4)
void cheb_fused(const float* __restrict__ x,
                const float* __restrict__ S,
                const float* __restrict__ Att,
                const unsigned short* __restrict__ thT,
                const unsigned short* __restrict__ xT,
                float* __restrict__ out)
{
    __shared__ __align__(16) char smem[30208];
    float*          sru = (float*)smem;                      // [32][113] f32 (S rows u, my v-cols)
    unsigned short* A1  = (unsigned short*)(smem + 14464);   // [112][32] bf16
    unsigned short* A2  = (unsigned short*)(smem + 21632);   // [112][32] bf16
    unsigned short* ys  = (unsigned short*)smem;             // [112][72] (epilogue, aliases sru/A1)
    unsigned short* ThS = (unsigned short*)(smem + 16128);   // [64][72]  (epilogue, aliases A1/A2)
    float* dbuf = (float*)(smem + 28800);                    // [112] d accum -> cbuf
    float* sdb  = (float*)(smem + 29248);                    // [112] S[v][v]
    float* adb  = (float*)(smem + 29696);                    // [112] Att[v][v]

    const int tid = threadIdx.x;
    const int b = blockIdx.x >> 1, h = blockIdx.x & 1;
    const int n = b >> 6;
    const int v0 = h * 112;
    const int NVL = h ? 96 : 112;     // local v-rows
    const int NV4 = NVL >> 2;         // float4 slots per sru row

    const float* __restrict__ Sp  = S   + (size_t)b * (V * V);
    const float* __restrict__ Ap  = Att + (size_t)n * (V * V);
    const float* __restrict__ xp  = x   + (size_t)b * (V * F);
    const unsigned short* __restrict__ xTp = xT + (size_t)b * (64 * 224);
    float* __restrict__ op = out + (size_t)b * (V * F);

    if (tid < 112) { dbuf[tid] = 0.f; sdb[tid] = 0.f; adb[tid] = 0.f; }

    const int wave = tid >> 6, lane = tid & 63, q = lane >> 4, ln = lane & 15;
    int myBase, myCnt;
    if (h == 0) { myCnt = (wave < 3) ? 2 : 1; myBase = 2 * wave; }        // tiles 0..6
    else        { myCnt = (wave < 2) ? 2 : 1; myBase = (wave < 2) ? 2 * wave : 2 + wave; } // 0..5

    f32x4 acc1[2][4], acc2[2][4];
    #pragma unroll
    for (int i = 0; i < 2; ++i)
        #pragma unroll
        for (int j = 0; j < 4; ++j) { acc1[i][j] = (f32x4)0.f; acc2[i][j] = (f32x4)0.f; }

    // S^T slab register prefetch: rows u (32), cols = my v-range
    float4 spf[4];
    auto load_sru = [&](int kt) {
        #pragma unroll
        for (int c = 0; c < 4; ++c) {
            const int idx = tid + 256 * c;
            const int ul = idx >> 5, sl = idx & 31;
            const int u = 32 * kt + ul, vv = v0 + 4 * sl;
            float4 z = make_float4(0.f, 0.f, 0.f, 0.f);
            if (sl < NV4 && u < V && vv < V)
                z = *(const float4*)&Sp[u * V + vv];     // 448B contiguous per u-row
            spf[c] = z;
        }
    };
    load_sru(0);
    __syncthreads();

    #pragma unroll 1
    for (int kt = 0; kt < 7; ++kt) {
        // ---- phase S: prefetched regs -> LDS sru ----
        #pragma unroll
        for (int c = 0; c < 4; ++c) {
            const int idx = tid + 256 * c;
            const int ul = idx >> 5, sl = idx & 31;
            if (sl < NV4) *(float4*)&sru[ul * 113 + 4 * sl] = spf[c];
        }
        __syncthreads();   // sru ready; MFMA(kt-1) done -> A-tiles free

        // ---- phase A: build A1/A2 + d/sd/ad; issue B-frag + next-slab loads ----
        short8 bcur[4];
        #pragma unroll
        for (int ft = 0; ft < 4; ++ft)
            bcur[ft] = *(const short8*)&xTp[(16 * ft + ln) * 224 + 32 * kt + 8 * q];
        #pragma unroll
        for (int c = 0; c < 4; ++c) {
            const int idx = tid + 256 * c;
            if (idx < NVL * 8) {
                const int vl = idx >> 3, ug = idx & 7;
                const int v = v0 + vl;
                const bool vok = v < V;
                const int u0 = 32 * kt + 4 * ug;
                float4 sc = make_float4(0.f, 0.f, 0.f, 0.f);
                if (vok && u0 < V) sc = *(const float4*)&Sp[v * V + u0];
                float rs = 0.f;
                u16x4 w1, w2;
                #pragma unroll
                for (int j = 0; j < 4; ++j) {
                    const int u = u0 + j;
                    const bool ok = vok && (u < V);
                    float att = 0.f, srt = 0.f;
                    if (ok) {
                        att = Ap[u * V + v];                   // Att[u][v]
                        srt = sru[(4 * ug + j) * 113 + vl];    // S[u][v]
                    }
                    const float scj = (j == 0) ? sc.x : (j == 1) ? sc.y : (j == 2) ? sc.z : sc.w;
                    float m = fminf(scj, srt);
                    if (!ok) m = 0.f;
                    rs += m;                                   // d includes diagonal
                    float a1, a2;
                    if (u == v) {
                        a1 = 0.f; a2 = 0.f;
                        if (vok) { sdb[vl] = m; adb[vl] = att; }
                    } else {
                        a1 = -m * att;
                        a2 = 2.0f * m * m * att;
                    }
                    w1[j] = f2bf(a1); w2[j] = f2bf(a2);
                }
                *(u16x4*)&A1[vl * 32 + 4 * ug] = w1;
                *(u16x4*)&A2[vl * 32 + 4 * ug] = w2;
                rs += __shfl_xor(rs, 1); rs += __shfl_xor(rs, 2); rs += __shfl_xor(rs, 4);
                if (ug == 0 && vok) dbuf[vl] += rs;            // unique writer per vl per kt
            }
        }
        if (kt < 6) load_sru(kt + 1);      // in flight through barrier drain
        __syncthreads();   // A-tiles ready

        // ---- phase M: MFMA ----
        #pragma unroll
        for (int vi = 0; vi < 2; ++vi) {
            if (vi < myCnt) {
                const int row = (myBase + vi) * 16 + ln;
                const short8 af1 = *(const short8*)&A1[row * 32 + 8 * q];
                const short8 af2 = *(const short8*)&A2[row * 32 + 8 * q];
                #pragma unroll
                for (int ft = 0; ft < 4; ++ft) {
                    acc1[vi][ft] = __builtin_amdgcn_mfma_f32_16x16x32_bf16(af1, bcur[ft], acc1[vi][ft], 0, 0, 0);
                    acc2[vi][ft] = __builtin_amdgcn_mfma_f32_16x16x32_bf16(af2, bcur[ft], acc2[vi][ft], 0, 0, 0);
                }
            }
        }
    }

    __syncthreads();
    if (tid < 112) dbuf[tid] = dbuf[tid] - 1.0f - sdb[tid];   // cbuf = d - 1 - S_vv

    // ---- epilogue: out-tiles += mfma(ys_k, ThT_k) for k = 1, 2, 0 ----
    f32x4 ot[2][4];
    #pragma unroll
    for (int i = 0; i < 2; ++i)
        #pragma unroll
        for (int j = 0; j < 4; ++j) ot[i][j] = (f32x4)0.f;

    #pragma unroll
    for (int pass = 0; pass < 3; ++pass) {
        const int k = (pass == 0) ? 1 : (pass == 1) ? 2 : 0;
        __syncthreads();   // prev MFMA reads of ys/ThS (and A-tiles/sru) done

        if (k == 0) {
            for (int idx = tid; idx < NVL * 16; idx += 256) {
                const int vl = idx >> 4, fg = idx & 15;
                const int v = v0 + vl;
                u16x4 w; w[0] = 0; w[1] = 0; w[2] = 0; w[3] = 0;
                if (v < V) {
                    const float av = adb[vl];
                    const float4 xv = *(const float4*)&xp[v * F + 4 * fg];
                    w[0] = f2bf(av * xv.x); w[1] = f2bf(av * xv.y);
                    w[2] = f2bf(av * xv.z); w[3] = f2bf(av * xv.w);
                }
                *(u16x4*)&ys[vl * 72 + 4 * fg] = w;
            }
        } else {
            #pragma unroll
            for (int vi = 0; vi < 2; ++vi) {
                if (vi < myCnt) {
                    const int lt = myBase + vi;
                    #pragma unroll
                    for (int ft = 0; ft < 4; ++ft) {
                        const f32x4 a = (k == 1) ? acc1[vi][ft] : acc2[vi][ft];
                        #pragma unroll
                        for (int reg = 0; reg < 4; ++reg) {
                            const int vl = lt * 16 + 4 * q + reg;
                            const int v = v0 + vl;
                            float val = 0.f;
                            if (v < V) {
                                const float cc = dbuf[vl];
                                const float dc = ((k == 1) ? cc : (2.0f * cc * cc - 1.0f)) * adb[vl];
                                val = a[reg] + dc * xp[v * F + 16 * ft + ln];
                            }
                            ys[vl * 72 + 16 * ft + ln] = f2bf(val);
                        }
                    }
                }
            }
        }
        for (int idx = tid; idx < 512; idx += 256) {
            const int fo = idx >> 3, ch = idx & 7;
            *(u16x8*)&ThS[fo * 72 + 8 * ch] =
                *(const u16x8*)&thT[k * 4096 + fo * 64 + 8 * ch];
        }
        __syncthreads();
        #pragma unroll
        for (int vi = 0; vi < 2; ++vi) {
            if (vi < myCnt) {
                const int vrow = (myBase + vi) * 16 + ln;
                #pragma unroll
                for (int ks = 0; ks < 2; ++ks) {
                    const short8 af = *(const short8*)&ys[vrow * 72 + 32 * ks + 8 * q];
                    #pragma unroll
                    for (int fot = 0; fot < 4; ++fot) {
                        const short8 bf = *(const short8*)&ThS[(16 * fot + ln) * 72 + 32 * ks + 8 * q];
                        ot[vi][fot] = __builtin_amdgcn_mfma_f32_16x16x32_bf16(af, bf, ot[vi][fot], 0, 0, 0);
                    }
                }
            }
        }
    }

    // ---- relu + store ----
    #pragma unroll
    for (int vi = 0; vi < 2; ++vi) {
        if (vi < myCnt) {
            const int lt = myBase + vi;
            #pragma unroll
            for (int fot = 0; fot < 4; ++fot) {
                #pragma unroll
                for (int reg = 0; reg < 4; ++reg) {
                    const int v = v0 + lt * 16 + 4 * q + reg;
                    if (v < V)
                        op[v * F + 16 * fot + ln] = fmaxf(ot[vi][fot][reg], 0.f);
                }
            }
        }
    }
}

} // namespace

extern "C" void kernel_launch(void* const* d_in, const int* in_sizes, int n_in,
                              void* d_out, int out_size, void* d_ws, size_t ws_size,
                              hipStream_t stream) {
    const float* x     = (const float*)d_in[0];
    const float* Att   = (const float*)d_in[1];
    const float* S     = (const float*)d_in[2];
    const float* Theta = (const float*)d_in[3];
    float* out         = (float*)d_out;

    char* ws = (char*)d_ws;
    unsigned short* xT  = (unsigned short*)(ws + WS_XT);
    unsigned short* thT = (unsigned short*)(ws + WS_THT);

    hipLaunchKernelGGL(prep_misc,  dim3(NT + 1), dim3(256), 0, stream, x, Theta, xT, thT);
    hipLaunchKernelGGL(cheb_fused, dim3(2 * NT), dim3(256), 0, stream,
                       x, S, Att, thT, xT, out);
}

// Round 4
// 310.070 us; speedup vs baseline: 1.1119x; 1.1119x over previous
//
#include <hip/hip_runtime.h>

namespace {

typedef __attribute__((ext_vector_type(8)))  short          short8;
typedef __attribute__((ext_vector_type(8)))  unsigned short u16x8;
typedef __attribute__((ext_vector_type(4)))  unsigned short u16x4;
typedef __attribute__((ext_vector_type(4)))  float          f32x4;

constexpr int V  = 200;
constexpr int F  = 64;
constexpr int NT = 512;   // N*T

// ---- ws layout (bytes) ----
constexpr size_t WS_XT  = 0;            // ushort [512][64][224] = 14,680,064  (x^T bf16, zero-padded u>=200)
constexpr size_t WS_THT = 14680064;     // ushort [3][64][64]    =     24,576

__device__ __forceinline__ unsigned short f2bf(float x) {
    union { float f; unsigned u; } c; c.f = x;
    unsigned r = c.u + 0x7FFF + ((c.u >> 16) & 1);
    return (unsigned short)(r >> 16);
}
__device__ __forceinline__ float bf2f(unsigned short h) {
    union { unsigned u; float f; } c; c.u = ((unsigned)h) << 16;
    return c.f;
}

// ============ P: xT[b][f][u] = bf16(x[b][u][f]) (513th block: ThT) ============
__global__ __launch_bounds__(256)
void prep_misc(const float* __restrict__ x,
               const float* __restrict__ Theta,
               unsigned short* __restrict__ xT,
               unsigned short* __restrict__ thT)
{
    __shared__ __align__(16) char smem[30464];
    const int bb = blockIdx.x, tid = threadIdx.x;
    if (bb < NT) {
        unsigned short* xs = (unsigned short*)smem;    // [224][68] bf16
        const float* __restrict__ xp = x + (size_t)bb * (V * F);
        for (int idx = tid; idx < 224 * 16; idx += 256) {
            const int u = idx >> 4, fg = idx & 15;
            u16x4 w; w[0] = 0; w[1] = 0; w[2] = 0; w[3] = 0;
            if (u < V) {
                const float4 v4 = *(const float4*)&xp[u * F + 4 * fg];
                w[0] = f2bf(v4.x); w[1] = f2bf(v4.y); w[2] = f2bf(v4.z); w[3] = f2bf(v4.w);
            }
            *(u16x4*)&xs[u * 68 + 4 * fg] = w;
        }
        __syncthreads();
        unsigned short* xo = xT + (size_t)bb * (64 * 224);
        for (int it = 0; it < 8; ++it) {
            const int wid = tid + 256 * it;            // 0..2047
            const int f = wid >> 5, sl = wid & 31;     // 64 f-rows x 32 slots (28 valid)
            if (sl < 28) {
                u16x8 w;
                #pragma unroll
                for (int j = 0; j < 8; ++j) w[j] = xs[(8 * sl + j) * 68 + f];
                *(u16x8*)&xo[f * 224 + 8 * sl] = w;    // 448B contiguous per f-row
            }
        }
    } else {
        float* T = (float*)smem;                       // [64][65] f32
        for (int k = 0; k < 3; ++k) {
            __syncthreads();
            for (int idx = tid; idx < 4096; idx += 256)
                T[(idx >> 6) * 65 + (idx & 63)] = Theta[k * 4096 + idx];
            __syncthreads();
            for (int idx = tid; idx < 4096; idx += 256) {
                const int fo = idx >> 6, f = idx & 63;
                thT[k * 4096 + fo * 64 + f] = f2bf(T[f * 65 + fo]);
            }
        }
    }
}

// ============ G: fused kernel, slab-staged S^T AND Att^T ============
// grid 1024, swizzled so the two v-halves of batch b share an XCD.
// Per kt (32 u's): LDS-stage S^T + Att^T slabs (reg-prefetched, coalesced
// row reads) -> build A1/A2 bf16 (A1=-m*Att[u][v], A2=2m^2*Att[u][v],
// m=min(S[v][u],S[u][v])) + d accum -> MFMA. Epilogue: LDS-staged x,
// Chebyshev diag terms + Theta contraction + relu.
__global__ __launch_bounds__(256, 3)
void cheb_fused(const float* __restrict__ x,
                const float* __restrict__ S,
                const float* __restrict__ Att,
                const unsigned short* __restrict__ thT,
                const unsigned short* __restrict__ xT,
                float* __restrict__ out)
{
    __shared__ __align__(16) char smem[44608];
    float*          sru = (float*)smem;                      // [32][113] f32  S[u][v-range]
    float*          asu = (float*)(smem + 14464);            // [32][113] f32  Att[u][v-range]
    unsigned short* A1  = (unsigned short*)(smem + 28928);   // [112][32] bf16
    unsigned short* A2  = (unsigned short*)(smem + 36096);   // [112][32] bf16
    unsigned short* ys  = (unsigned short*)smem;             // [112][72] (epilogue)
    unsigned short* ThS = (unsigned short*)(smem + 16128);   // [64][72]  (epilogue)
    unsigned short* xe  = (unsigned short*)(smem + 25344);   // [112][72] bf16 x (epilogue)
    float* dbuf = (float*)(smem + 43264);                    // [112] d accum -> cbuf
    float* sdb  = (float*)(smem + 43712);                    // [112] S[v][v]
    float* adb  = (float*)(smem + 44160);                    // [112] Att[v][v]

    const int tid = threadIdx.x;
    // swizzle: blocks u and u+8 (same XCD, round-robin mod 8) are the two
    // halves of the same b -> shared xT/S/Att in that XCD's L2.
    const int ub = blockIdx.x;
    const int h  = (ub >> 3) & 1;
    const int b  = (ub & 7) | ((ub >> 4) << 3);
    const int n  = b >> 6;
    const int v0 = h * 112;
    const int NVL = h ? 96 : 112;     // local v-rows
    const int NV4 = NVL >> 2;         // float4 slots per slab row

    const float* __restrict__ Sp  = S   + (size_t)b * (V * V);
    const float* __restrict__ Ap  = Att + (size_t)n * (V * V);
    const float* __restrict__ xp  = x   + (size_t)b * (V * F);
    const unsigned short* __restrict__ xTp = xT + (size_t)b * (64 * 224);
    float* __restrict__ op = out + (size_t)b * (V * F);

    if (tid < 112) { dbuf[tid] = 0.f; sdb[tid] = 0.f; adb[tid] = 0.f; }

    const int wave = tid >> 6, lane = tid & 63, q = lane >> 4, ln = lane & 15;
    int myBase, myCnt;
    if (h == 0) { myCnt = (wave < 3) ? 2 : 1; myBase = 2 * wave; }        // tiles 0..6
    else        { myCnt = (wave < 2) ? 2 : 1; myBase = (wave < 2) ? 2 * wave : 2 + wave; } // 0..5

    f32x4 acc1[2][4], acc2[2][4];
    #pragma unroll
    for (int i = 0; i < 2; ++i)
        #pragma unroll
        for (int j = 0; j < 4; ++j) { acc1[i][j] = (f32x4)0.f; acc2[i][j] = (f32x4)0.f; }

    // slab register prefetch: rows u (32), cols = my v-range; S and Att
    float4 spf[4], apf[4];
    auto load_slab = [&](int kt) {
        #pragma unroll
        for (int c = 0; c < 4; ++c) {
            const int idx = tid + 256 * c;
            const int ul = idx >> 5, sl = idx & 31;
            const int u = 32 * kt + ul, vv = v0 + 4 * sl;
            float4 z = make_float4(0.f, 0.f, 0.f, 0.f);
            float4 a = make_float4(0.f, 0.f, 0.f, 0.f);
            if (sl < NV4 && u < V && vv < V) {
                z = *(const float4*)&Sp[u * V + vv];     // contiguous per u-row
                a = *(const float4*)&Ap[u * V + vv];
            }
            spf[c] = z; apf[c] = a;
        }
    };
    load_slab(0);
    __syncthreads();

    #pragma unroll 1
    for (int kt = 0; kt < 7; ++kt) {
        // ---- phase S: prefetched regs -> LDS slabs ----
        #pragma unroll
        for (int c = 0; c < 4; ++c) {
            const int idx = tid + 256 * c;
            const int ul = idx >> 5, sl = idx & 31;
            if (sl < NV4) {
                *(float4*)&sru[ul * 113 + 4 * sl] = spf[c];
                *(float4*)&asu[ul * 113 + 4 * sl] = apf[c];
            }
        }
        __syncthreads();   // slabs ready; MFMA(kt-1) done -> A-tiles free

        // ---- phase A: build A1/A2 + d/sd/ad; issue B-frag + next-slab loads ----
        short8 bcur[4];
        #pragma unroll
        for (int ft = 0; ft < 4; ++ft)
            bcur[ft] = *(const short8*)&xTp[(16 * ft + ln) * 224 + 32 * kt + 8 * q];
        #pragma unroll
        for (int c = 0; c < 4; ++c) {
            const int idx = tid + 256 * c;
            if (idx < NVL * 8) {
                const int vl = idx >> 3, ug = idx & 7;
                const int v = v0 + vl;
                const bool vok = v < V;
                const int u0 = 32 * kt + 4 * ug;
                float4 sc = make_float4(0.f, 0.f, 0.f, 0.f);
                if (vok && u0 < V) sc = *(const float4*)&Sp[v * V + u0];
                float rs = 0.f;
                u16x4 w1, w2;
                #pragma unroll
                for (int j = 0; j < 4; ++j) {
                    const int u = u0 + j;
                    const bool ok = vok && (u < V);
                    float att = 0.f, srt = 0.f;
                    if (ok) {
                        att = asu[(4 * ug + j) * 113 + vl];    // Att[u][v] (LDS slab)
                        srt = sru[(4 * ug + j) * 113 + vl];    // S[u][v]
                    }
                    const float scj = (j == 0) ? sc.x : (j == 1) ? sc.y : (j == 2) ? sc.z : sc.w;
                    float m = fminf(scj, srt);
                    if (!ok) m = 0.f;
                    rs += m;                                   // d includes diagonal
                    float a1, a2;
                    if (u == v) {
                        a1 = 0.f; a2 = 0.f;
                        if (vok) { sdb[vl] = m; adb[vl] = att; }
                    } else {
                        a1 = -m * att;
                        a2 = 2.0f * m * m * att;
                    }
                    w1[j] = f2bf(a1); w2[j] = f2bf(a2);
                }
                *(u16x4*)&A1[vl * 32 + 4 * ug] = w1;
                *(u16x4*)&A2[vl * 32 + 4 * ug] = w2;
                rs += __shfl_xor(rs, 1); rs += __shfl_xor(rs, 2); rs += __shfl_xor(rs, 4);
                if (ug == 0 && vok) dbuf[vl] += rs;            // unique writer per vl per kt
            }
        }
        if (kt < 6) load_slab(kt + 1);      // in flight through barrier drain
        __syncthreads();   // A-tiles ready

        // ---- phase M: MFMA ----
        #pragma unroll
        for (int vi = 0; vi < 2; ++vi) {
            if (vi < myCnt) {
                const int row = (myBase + vi) * 16 + ln;
                const short8 af1 = *(const short8*)&A1[row * 32 + 8 * q];
                const short8 af2 = *(const short8*)&A2[row * 32 + 8 * q];
                #pragma unroll
                for (int ft = 0; ft < 4; ++ft) {
                    acc1[vi][ft] = __builtin_amdgcn_mfma_f32_16x16x32_bf16(af1, bcur[ft], acc1[vi][ft], 0, 0, 0);
                    acc2[vi][ft] = __builtin_amdgcn_mfma_f32_16x16x32_bf16(af2, bcur[ft], acc2[vi][ft], 0, 0, 0);
                }
            }
        }
    }

    __syncthreads();                       // K loop fully done; A-tiles/slabs dead
    if (tid < 112) dbuf[tid] = dbuf[tid] - 1.0f - sdb[tid];   // cbuf = d - 1 - S_vv
    // stage x -> bf16 xe (read once, used by all 3 epilogue passes)
    for (int idx = tid; idx < NVL * 16; idx += 256) {
        const int vl = idx >> 4, fg = idx & 15;
        const int v = v0 + vl;
        u16x4 w; w[0] = 0; w[1] = 0; w[2] = 0; w[3] = 0;
        if (v < V) {
            const float4 xv = *(const float4*)&xp[v * F + 4 * fg];
            w[0] = f2bf(xv.x); w[1] = f2bf(xv.y); w[2] = f2bf(xv.z); w[3] = f2bf(xv.w);
        }
        *(u16x4*)&xe[vl * 72 + 4 * fg] = w;
    }

    // ---- epilogue: out-tiles += mfma(ys_k, ThT_k) for k = 1, 2, 0 ----
    f32x4 ot[2][4];
    #pragma unroll
    for (int i = 0; i < 2; ++i)
        #pragma unroll
        for (int j = 0; j < 4; ++j) ot[i][j] = (f32x4)0.f;

    #pragma unroll
    for (int pass = 0; pass < 3; ++pass) {
        const int k = (pass == 0) ? 1 : (pass == 1) ? 2 : 0;
        __syncthreads();   // xe/cbuf ready (pass 0); prev MFMA reads done

        if (k == 0) {
            for (int idx = tid; idx < NVL * 16; idx += 256) {
                const int vl = idx >> 4, fg = idx & 15;
                const int v = v0 + vl;
                u16x4 w; w[0] = 0; w[1] = 0; w[2] = 0; w[3] = 0;
                if (v < V) {
                    const float av = adb[vl];
                    #pragma unroll
                    for (int e = 0; e < 4; ++e)
                        w[e] = f2bf(av * bf2f(xe[vl * 72 + 4 * fg + e]));
                }
                *(u16x4*)&ys[vl * 72 + 4 * fg] = w;
            }
        } else {
            #pragma unroll
            for (int vi = 0; vi < 2; ++vi) {
                if (vi < myCnt) {
                    const int lt = myBase + vi;
                    #pragma unroll
                    for (int ft = 0; ft < 4; ++ft) {
                        const f32x4 a = (k == 1) ? acc1[vi][ft] : acc2[vi][ft];
                        #pragma unroll
                        for (int reg = 0; reg < 4; ++reg) {
                            const int vl = lt * 16 + 4 * q + reg;
                            const int v = v0 + vl;
                            float val = 0.f;
                            if (v < V) {
                                const float cc = dbuf[vl];
                                const float dc = ((k == 1) ? cc : (2.0f * cc * cc - 1.0f)) * adb[vl];
                                val = a[reg] + dc * bf2f(xe[vl * 72 + 16 * ft + ln]);
                            }
                            ys[vl * 72 + 16 * ft + ln] = f2bf(val);
                        }
                    }
                }
            }
        }
        for (int idx = tid; idx < 512; idx += 256) {
            const int fo = idx >> 3, ch = idx & 7;
            *(u16x8*)&ThS[fo * 72 + 8 * ch] =
                *(const u16x8*)&thT[k * 4096 + fo * 64 + 8 * ch];
        }
        __syncthreads();
        #pragma unroll
        for (int vi = 0; vi < 2; ++vi) {
            if (vi < myCnt) {
                const int vrow = (myBase + vi) * 16 + ln;
                #pragma unroll
                for (int ks = 0; ks < 2; ++ks) {
                    const short8 af = *(const short8*)&ys[vrow * 72 + 32 * ks + 8 * q];
                    #pragma unroll
                    for (int fot = 0; fot < 4; ++fot) {
                        const short8 bf = *(const short8*)&ThS[(16 * fot + ln) * 72 + 32 * ks + 8 * q];
                        ot[vi][fot] = __builtin_amdgcn_mfma_f32_16x16x32_bf16(af, bf, ot[vi][fot], 0, 0, 0);
                    }
                }
            }
        }
    }

    // ---- relu + store ----
    #pragma unroll
    for (int vi = 0; vi < 2; ++vi) {
        if (vi < myCnt) {
            const int lt = myBase + vi;
            #pragma unroll
            for (int fot = 0; fot < 4; ++fot) {
                #pragma unroll
                for (int reg = 0; reg < 4; ++reg) {
                    const int v = v0 + lt * 16 + 4 * q + reg;
                    if (v < V)
                        op[v * F + 16 * fot + ln] = fmaxf(ot[vi][fot][reg], 0.f);
                }
            }
        }
    }
}

} // namespace

extern "C" void kernel_launch(void* const* d_in, const int* in_sizes, int n_in,
                              void* d_out, int out_size, void* d_ws, size_t ws_size,
                              hipStream_t stream) {
    const float* x     = (const float*)d_in[0];
    const float* Att   = (const float*)d_in[1];
    const float* S     = (const float*)d_in[2];
    const float* Theta = (const float*)d_in[3];
    float* out         = (float*)d_out;

    char* ws = (char*)d_ws;
    unsigned short* xT  = (unsigned short*)(ws + WS_XT);
    unsigned short* thT = (unsigned short*)(ws + WS_THT);

    hipLaunchKernelGGL(prep_misc,  dim3(NT + 1), dim3(256), 0, stream, x, Theta, xT, thT);
    hipLaunchKernelGGL(cheb_fused, dim3(2 * NT), dim3(256), 0, stream,
                       x, S, Att, thT, xT, out);
}